// Round 8
// baseline (225.133 us; speedup 1.0000x reference)
//
#include <hip/hip_runtime.h>
#include <math.h>

#define BTOT 131072
#define NBK 3
#define SS 16
#define NA 9
#define BAD 25      // SS+NA
#define STR 28      // padded row stride in the fp32 weight image
#define VD 128
#define CM 10
#define OUTD 51     // NBK*SS + 3
#define EPS 1e-8f

// ---- fp32 folded-weight image (float offsets in ws) ----
#define O_GQK  0        // 25 x 28  full Wq^T Wk (f>24 zeroed)
#define O_GQQ  700      // 25 x 28  lower-tri (off-diag x2) of Wq^T Wq (f>e zeroed)
#define O_GKK  1400     // 25 x 28  lower-tri (off-diag x2) of Wk^T Wk
#define O_V1   2100     // 28: Wq^T bk   (V1,V2,VQ,VK consecutive: base + p4*STR)
#define O_V2   2128     // 28: Wk^T bq
#define O_VQ   2156     // 28: Wq^T bq
#define O_VK   2184     // 28: Wk^T bk
#define O_C    2212     // c0, cq, ck, pad
#define O_M    2216     // (dead region)
#define O_B2   7976     // 16
#define O_WC1  7992     // 10 x 84
#define O_BC1  8832     // 12
#define O_WC2  8844     // 3 x 12
#define O_BC2  8880     // 4
#define LDS_F  8884
// ---- bf16 MFMA-packed B-fragments appended after the fp32 image ----
#define O_PKM  LDS_F          // 4096 ushorts = 2048 floats
#define O_PKW2 (LDS_F + 2048) // 2048 ushorts = 1024 floats
#define PKM_N  4096
#define PKW2_N 2048

#define NDOT  (O_M + PKM_N)   // 2216 fp32 dots + 4096 pkM dots
#define NCOPY (16 + 840 + 12 + 36 + 4 + PKW2_N)

typedef __attribute__((ext_vector_type(8))) short short8;
typedef __attribute__((ext_vector_type(4))) float floatx4;
typedef __attribute__((ext_vector_type(2))) float float2v;

__device__ __forceinline__ float fast_sigmoid(float x) {
    return __builtin_amdgcn_rcpf(1.0f + __expf(-x));
}

__device__ __forceinline__ unsigned short f2bf(float f) {
    unsigned int u = __float_as_uint(f);
    u += 0x7FFFu + ((u >> 16) & 1u);   // round-to-nearest-even
    return (unsigned short)(u >> 16);
}

// VOP3P packed fp32 (2 FMA/instr) — hipcc does not auto-generate these.
__device__ __forceinline__ float2v pk_fma(float2v a, float2v b, float2v c) {
    float2v d;
    asm("v_pk_fma_f32 %0, %1, %2, %3" : "=v"(d) : "v"(a), "v"(b), "v"(c));
    return d;
}
__device__ __forceinline__ float2v pk_mul(float2v a, float2v b) {
    float2v d;
    asm("v_pk_mul_f32 %0, %1, %2" : "=v"(d) : "v"(a), "v"(b));
    return d;
}
__device__ __forceinline__ unsigned int cvt_pk_bf16(float lo, float hi) {
    unsigned int r;
    asm("v_cvt_pk_bf16_f32 %0, %1, %2" : "=v"(r) : "v"(lo), "v"(hi));
    return r;
}

// quad_perm broadcast within each 4-lane group (DPP ctrl 0x00..0xFF)
#define QB0(x) __int_as_float(__builtin_amdgcn_mov_dpp(__float_as_int(x), 0x00, 0xF, 0xF, false))
#define QB1(x) __int_as_float(__builtin_amdgcn_mov_dpp(__float_as_int(x), 0x55, 0xF, 0xF, false))
#define QB2(x) __int_as_float(__builtin_amdgcn_mov_dpp(__float_as_int(x), 0xAA, 0xF, 0xF, false))
#define QB3(x) __int_as_float(__builtin_amdgcn_mov_dpp(__float_as_int(x), 0xFF, 0xF, 0xF, false))

// ---------------- prep: wave-per-output 128-length dot products ----------------
__global__ __launch_bounds__(256) void prep_dots(
    const float* __restrict__ Wq, const float* __restrict__ bq,
    const float* __restrict__ Wk, const float* __restrict__ bk,
    const float* __restrict__ Wv, const float* __restrict__ bv,
    const float* __restrict__ W1, const float* __restrict__ b1,
    float* __restrict__ ws) {
    int lane = threadIdx.x & 63;
    int gidx = blockIdx.x * 4 + (threadIdx.x >> 6);
    if (gidx >= NDOT) return;

    const float* pa = bq;  const float* pb = bk;   // safe defaults
    int sa = 1, sb = 1;
    float scale = 1.0f, bias = 0.0f;
    bool zero = false;
    bool isbf = false; int bfpos = 0;

    if (gidx < O_M) {
        int idx = gidx;
        if (idx < O_GQQ) {
            int e = idx / STR, f = idx % STR;
            if (f < BAD) { pa = Wq + e; sa = BAD; pb = Wk + f; sb = BAD; }
            else zero = true;
        } else if (idx < O_GKK) {
            int j = idx - O_GQQ; int e = j / STR, f = j % STR;
            if (f < BAD && f <= e) { pa = Wq + e; sa = BAD; pb = Wq + f; sb = BAD; scale = (f == e) ? 1.0f : 2.0f; }
            else zero = true;
        } else if (idx < O_V1) {
            int j = idx - O_GKK; int e = j / STR, f = j % STR;
            if (f < BAD && f <= e) { pa = Wk + e; sa = BAD; pb = Wk + f; sb = BAD; scale = (f == e) ? 1.0f : 2.0f; }
            else zero = true;
        } else if (idx < O_V2) {
            int e = idx - O_V1;
            if (e < BAD) { pa = Wq + e; sa = BAD; pb = bk; }
            else zero = true;
        } else if (idx < O_VQ) {
            int e = idx - O_V2;
            if (e < BAD) { pa = Wk + e; sa = BAD; pb = bq; }
            else zero = true;
        } else if (idx < O_VK) {
            int e = idx - O_VQ;
            if (e < BAD) { pa = Wq + e; sa = BAD; pb = bq; }
            else zero = true;
        } else if (idx < O_C) {
            int e = idx - O_VK;
            if (e < BAD) { pa = Wk + e; sa = BAD; pb = bk; }
            else zero = true;
        } else {
            int j = idx - O_C;
            if (j == 0)      { pa = bq; pb = bk; }
            else if (j == 1) { pa = bq; pb = bq; }
            else if (j == 2) { pa = bk; pb = bk; }
            else zero = true;
        }
    } else {
        // pkM B-frag: B[k][n], n = tile*16 + (l&15), k = (l>>4)*8 + j
        int p = gidx - O_M;
        isbf = true; bfpos = p;
        int l2 = (p >> 3) & 63, j = p & 7;
        int n = (p >> 9) * 16 + (l2 & 15);
        int k = ((l2 >> 4) << 3) + j;
        if (k < BAD)       { pa = W1 + n * VD; pb = Wv + k; sb = BAD; scale = 2.0f; }
        else if (k == BAD) { pa = W1 + n * VD; pb = bv; scale = 2.0f; bias = 2.0f * b1[n]; }
        else zero = true;
    }

    float s = 0.0f;
    if (!zero)
        s = pa[sa * lane] * pb[sb * lane] + pa[sa * (lane + 64)] * pb[sb * (lane + 64)];
    #pragma unroll
    for (int off = 1; off < 64; off <<= 1) s += __shfl_xor(s, off);
    float val = zero ? 0.0f : (s * scale + bias);
    if (lane == 0) {
        if (isbf) ((unsigned short*)(ws + O_PKM))[bfpos] = f2bf(val);
        else ws[gidx] = val;
    }
}

__global__ __launch_bounds__(256) void prep_copy(
    const float* __restrict__ W2, const float* __restrict__ b2,
    const float* __restrict__ Wc1, const float* __restrict__ bc1,
    const float* __restrict__ Wc2, const float* __restrict__ bc2,
    float* __restrict__ ws) {
    int c = blockIdx.x * 256 + threadIdx.x;
    if (c >= NCOPY) return;
    if (c < 16) { ws[O_B2 + c] = b2[c]; return; }
    c -= 16;
    if (c < 840) {
        int m = c / 84, r = c % 84, i = r / STR, f = r % STR;
        ws[O_WC1 + c] = (f < BAD) ? Wc1[m * (NBK * BAD) + i * BAD + f] : 0.0f;
        return;
    }
    c -= 840;
    if (c < 12) { ws[O_BC1 + c] = (c < CM) ? bc1[c] : 0.0f; return; }
    c -= 12;
    if (c < 36) { int o = c / 12, mm = c % 12; ws[O_WC2 + c] = (mm < CM) ? Wc2[o * CM + mm] : 0.0f; return; }
    c -= 36;
    if (c < 4) { ws[O_BC2 + c] = (c < 3) ? bc2[c] : 0.0f; return; }
    c -= 4;
    // pkW2 B-frag: B[k][o], o = l&15, k = kt*32 + (l>>4)*8 + j
    int kt = c >> 9, l = (c >> 3) & 63, j = c & 7;
    int o = l & 15;
    int k = kt * 32 + ((l >> 4) << 3) + j;
    ((unsigned short*)(ws + O_PKW2))[c] = f2bf(W2[o * VD + k]);
}

// ---------------- fused main kernel: QUAD SPLIT + PACKED FP32 ----------------
// 4 lanes per element (p4 = lane&3), work SPLIT (~1.15x total work):
//   lin:  lane p4 -> vector p4 (V1/V2/VQ/VK consecutive, one per-lane base)
//   quad: lanes 0,1 = GQQ triangle (e parity); lanes 2,3 = GKK.  Uniform
//         ii=0..12,k<=ii loop: tri image's f>e zeros + ba2[.][12].y=0 make
//         phantom rows/cols self-masking (no divergence).
//   num:  e == p4 (mod 4) rows; be via cndmask selects.
//   conf: hidden units 3/3/2/2; outputs quad-reduced as partials.
//   a_tilde: lane p4 computes+stores row i=p4 (lane3 shadows row2, masked).
// Exchange: 12 quad_perm DPP broadcasts + ~30 shfl_xor (VALU-rate).
// Duplicated: ba build + softmax + exchange only. Wave supply doubles to 8192
// (2048 blocks x 4 waves) and the per-wave critical path ~0.65x of r7 -> both
// levers act on the measured dependency-latency-bound regime (r7: VALUBusy
// 52->40% at constant time). Phase 2: verified MFMA path, 3 tiles/wave.
__global__ __launch_bounds__(256) void main_kernel(
    const float* __restrict__ states, const float* __restrict__ action,
    const int* __restrict__ block_id,
    const float* __restrict__ ws, float* __restrict__ out) {
    __shared__ __align__(16) unsigned short At[192 * 40];   // 15360 B

    int t = threadIdx.x;
    int lane = t & 63;
    int p4 = t & 3;
    int le = t >> 2;                        // local element 0..63
    long elem = (long)blockIdx.x * 64 + le;

    const float* st = states + elem * (NBK * SS);
    const float* ac = action + elem * NA;
    const int* bid = block_id + elem * NBK;

    // ---- build ba as float2 pairs (duplicated across the quad; L1-hot) ----
    float2v ba2[NBK][13];
    #pragma unroll
    for (int i = 0; i < NBK; ++i) {
        const float4* s4 = (const float4*)(st + i * SS);
        float4 v0 = s4[0], v1 = s4[1], v2 = s4[2], v3 = s4[3];
        ba2[i][0] = float2v{v0.x, v0.y}; ba2[i][1] = float2v{v0.z, v0.w};
        ba2[i][2] = float2v{v1.x, v1.y}; ba2[i][3] = float2v{v1.z, v1.w};
        ba2[i][4] = float2v{v2.x, v2.y}; ba2[i][5] = float2v{v2.z, v2.w};
        ba2[i][6] = float2v{v3.x, v3.y}; ba2[i][7] = float2v{v3.z, v3.w};
        bool sel = (bid[i] == 1);
        float av[9];
        #pragma unroll
        for (int c = 0; c < 9; ++c) av[c] = sel ? ac[c] : -1.0f;
        ba2[i][8]  = float2v{av[0], av[1]};
        ba2[i][9]  = float2v{av[2], av[3]};
        ba2[i][10] = float2v{av[4], av[5]};
        ba2[i][11] = float2v{av[6], av[7]};
        ba2[i][12] = float2v{av[8], 0.0f};
    }

    // ---- linear vector p4: vecd[p] = vec_{p4} . ba_p ----
    float vecd[NBK];
    {
        const float2v* v2 = (const float2v*)(ws + O_V1 + p4 * STR);
        #pragma unroll
        for (int p = 0; p < NBK; ++p) {
            float2v a = {0.f, 0.f};
            #pragma unroll
            for (int k = 0; k < 13; ++k) a = pk_fma(v2[k], ba2[p][k], a);
            vecd[p] = a.x + a.y;
        }
    }
    // broadcasts: s1 (lane0), s2 (lane1), dq (lane2), dk (lane3)
    float s1b[NBK], s2b[NBK], dqb[NBK], dkb[NBK];
    #pragma unroll
    for (int p = 0; p < NBK; ++p) {
        s1b[p] = QB0(vecd[p]);
        s2b[p] = QB1(vecd[p]);
        dqb[p] = QB2(vecd[p]);
        dkb[p] = QB3(vecd[p]);
    }

    // ---- quadratic triangles: lanes 0,1 GQQ; 2,3 GKK; e parity by p4&1 ----
    float rn[NBK], qv[NBK], kv[NBK];
    {
        const float* gt = ws + (p4 >= 2 ? O_GKK : O_GQQ) + (p4 & 1) * STR;
        bool odd = (p4 & 1);
        float sn2p[NBK] = {0.f, 0.f, 0.f};
        #pragma unroll
        for (int ii = 0; ii < 13; ++ii) {   // e = 2*ii + (p4&1); phantom e=25 self-masked
            const float2v* g2 = (const float2v*)(gt + ii * 2 * STR);
            float2v a0 = {0.f, 0.f}, a1 = {0.f, 0.f}, a2 = {0.f, 0.f};
            #pragma unroll
            for (int k = 0; k <= ii; ++k) {
                a0 = pk_fma(g2[k], ba2[0][k], a0);
                a1 = pk_fma(g2[k], ba2[1][k], a1);
                a2 = pk_fma(g2[k], ba2[2][k], a2);
            }
            float p0 = a0.x + a0.y, p1 = a1.x + a1.y, p2 = a2.x + a2.y;
            float be0 = odd ? ba2[0][ii].y : ba2[0][ii].x;
            float be1 = odd ? ba2[1][ii].y : ba2[1][ii].x;
            float be2 = odd ? ba2[2][ii].y : ba2[2][ii].x;
            sn2p[0] = fmaf(be0, p0, sn2p[0]);
            sn2p[1] = fmaf(be1, p1, sn2p[1]);
            sn2p[2] = fmaf(be2, p2, sn2p[2]);
        }
        float cq = ws[O_C + 1], ck = ws[O_C + 2];
        float cc = (p4 < 2) ? cq : ck;
        #pragma unroll
        for (int p = 0; p < NBK; ++p) {
            float sn2 = sn2p[p] + __shfl_xor(sn2p[p], 1);       // parity halves
            float dv2 = (p4 < 2) ? dqb[p] : dkb[p];
            sn2 += 2.0f * dv2 + cc;
            rn[p] = __builtin_amdgcn_sqrtf(fmaxf(sn2, 0.0f));
            float orn = __shfl_xor(rn[p], 2);                   // GQQ<->GKK
            qv[p] = (p4 < 2) ? rn[p] : orn;
            kv[p] = (p4 < 2) ? orn : rn[p];
        }
    }

    // ---- bilinear numerators: rows e == p4 (mod 4); phantom rows self-masked
    float nm[NBK][NBK] = {{0.f,0.f,0.f},{0.f,0.f,0.f},{0.f,0.f,0.f}};
    {
        const float* gq = ws + O_GQK + p4 * STR;
        bool oddp = (p4 & 1), hip = (p4 & 2);
        #pragma unroll
        for (int ii = 0; ii < 7; ++ii) {   // e = 4*ii + p4
            const float2v* g2 = (const float2v*)(gq + ii * 4 * STR);
            float2v t20 = {0.f, 0.f}, t21 = {0.f, 0.f}, t22 = {0.f, 0.f};
            #pragma unroll
            for (int k = 0; k < 13; ++k) {
                t20 = pk_fma(g2[k], ba2[0][k], t20);
                t21 = pk_fma(g2[k], ba2[1][k], t21);
                t22 = pk_fma(g2[k], ba2[2][k], t22);
            }
            float t0 = t20.x + t20.y, t1 = t21.x + t21.y, t2s = t22.x + t22.y;
            #pragma unroll
            for (int i = 0; i < NBK; ++i) {
                float be;
                if (ii < 6) {
                    float c01 = oddp ? ba2[i][2 * ii].y     : ba2[i][2 * ii].x;
                    float c23 = oddp ? ba2[i][2 * ii + 1].y : ba2[i][2 * ii + 1].x;
                    be = hip ? c23 : c01;
                } else {
                    be = (p4 == 0) ? ba2[i][12].x : 0.0f;   // e=24 only on lane0
                }
                nm[i][0] = fmaf(be, t0, nm[i][0]);
                nm[i][1] = fmaf(be, t1, nm[i][1]);
                nm[i][2] = fmaf(be, t2s, nm[i][2]);
            }
        }
        #pragma unroll
        for (int i = 0; i < NBK; ++i)
            #pragma unroll
            for (int j = 0; j < NBK; ++j) {
                nm[i][j] += __shfl_xor(nm[i][j], 1);
                nm[i][j] += __shfl_xor(nm[i][j], 2);
            }
    }

    // ---- confidence MLP: units 3/3/2/2 per lane; quad-reduced partial outs --
    {
        int mstart = (p4 <= 2) ? 3 * p4 : 8;
        const float* wc = ws + O_WC1 + mstart * 84;   // per-lane base
        const float* bc = ws + O_BC1 + mstart;
        float hp[3];
        #pragma unroll
        for (int k = 0; k < 3; ++k) {
            float2v a2 = {0.f, 0.f};
            #pragma unroll
            for (int i = 0; i < NBK; ++i) {
                const float2v* w2 = (const float2v*)(wc + k * 84 + i * STR);
                #pragma unroll
                for (int p = 0; p < 13; ++p) a2 = pk_fma(w2[p], ba2[i][p], a2);
            }
            hp[k] = fast_sigmoid(bc[k] + a2.x + a2.y);
        }
        float po[3];
        #pragma unroll
        for (int o = 0; o < 3; ++o) {
            const float* w2r = ws + O_WC2 + o * 12 + mstart;
            float s = w2r[0] * hp[0] + w2r[1] * hp[1];
            float w3 = (p4 < 2) ? w2r[2] : 0.0f;       // 3rd unit only lanes 0,1
            s = fmaf(w3, hp[2], s);
            po[o] = s;
        }
        #pragma unroll
        for (int o = 0; o < 3; ++o) {
            po[o] += __shfl_xor(po[o], 1);
            po[o] += __shfl_xor(po[o], 2);
        }
        if (p4 == 0) {
            float* op = out + elem * OUTD;
            #pragma unroll
            for (int o = 0; o < 3; ++o)
                op[48 + o] = fast_sigmoid(po[o] + ws[O_BC2 + o]);
        }
    }

    // ---- softmax over j (duplicated across quad; cheap) ----
    float att[NBK][NBK];
    {
        float c0 = ws[O_C + 0];
        #pragma unroll
        for (int i = 0; i < NBK; ++i) {
            float dv[NBK];
            #pragma unroll
            for (int j = 0; j < NBK; ++j)
                dv[j] = (nm[i][j] + s1b[i] + s2b[j] + c0) *
                        __builtin_amdgcn_rcpf(fmaxf(qv[i] * kv[j], EPS));
            float mx = fmaxf(dv[0], fmaxf(dv[1], dv[2]));
            float e0 = __expf(dv[0] - mx);
            float e1 = __expf(dv[1] - mx);
            float e2 = __expf(dv[2] - mx);
            float inv = __builtin_amdgcn_rcpf(e0 + e1 + e2);
            att[i][0] = e0 * inv;
            att[i][1] = e1 * inv;
            att[i][2] = e2 * inv;
        }
    }

    // ---- a_tilde row i = p4 (lane3 shadows row 2; stores exec-masked) ----
    {
        float aw[NBK];
        #pragma unroll
        for (int j = 0; j < NBK; ++j) {
            float a01 = (p4 & 1) ? att[1][j] : att[0][j];
            aw[j] = (p4 >= 2) ? att[2][j] : a01;
        }
        int irow = (p4 < 2) ? p4 : 2;
        unsigned int* dst = (unsigned int*)&At[(le * 3 + irow) * 40];
        bool stq = (p4 < 3);
        float2v w0 = {aw[0], aw[0]}, w1 = {aw[1], aw[1]}, w2d = {aw[2], aw[2]};
        #pragma unroll
        for (int pr = 0; pr < 12; ++pr) {
            float2v v = pk_fma(ba2[0][pr], w0, pk_fma(ba2[1][pr], w1, pk_mul(ba2[2][pr], w2d)));
            if (stq) dst[pr] = cvt_pk_bf16(v.x, v.y);
        }
        float v24 = ba2[0][12].x * aw[0] + ba2[1][12].x * aw[1] + ba2[2][12].x * aw[2];
        if (stq) {
            dst[12] = cvt_pk_bf16(v24, 1.0f);   // hi = bf16(1.0) = 0x3F80
            dst[13] = 0u; dst[14] = 0u; dst[15] = 0u;
        }
    }

    // At is wave-private: each wave's quads wrote rows 48w..48w+47 and its
    // phase-2 tiles 3w..3w+2 read exactly those. Wave-local fence suffices.
    asm volatile("s_waitcnt lgkmcnt(0)" ::: "memory");

    // ================= phase 2: MFMA (3 tiles per wave, verified path) =======
    {
        int w = t >> 6;
        int m = lane & 15, q = lane >> 4;
        const short8* pkM = (const short8*)(ws + O_PKM);
        const short8* pkW2 = (const short8*)(ws + O_PKW2);
        float b2v = ws[O_B2 + m];
        long blockbase = (long)blockIdx.x * 64;
        int addrA = ((q & 1) ? (m + 32) : m) << 2;
        int addrB = addrA + 64;
        bool hiSel = (q >= 2);

        for (int tt = 0; tt < 3; ++tt) {
            int tile = w * 3 + tt;            // rows tile*16 .. +15 (0..191)
            short8 af = *(const short8*)&At[(tile * 16 + m) * 40 + q * 8];
            floatx4 accT[8];
            #pragma unroll
            for (int nt = 0; nt < 8; ++nt) {
                floatx4 z = {0.f, 0.f, 0.f, 0.f};
                accT[nt] = __builtin_amdgcn_mfma_f32_16x16x32_bf16(pkM[nt * 64 + lane], af, z, 0, 0, 0);
            }
            unsigned int pk[8][2];
            #pragma unroll
            for (int nt = 0; nt < 8; ++nt) {
                float x0 = fmaf(-2.0f, __builtin_amdgcn_rcpf(1.0f + __expf(accT[nt][0])), 1.0f);
                float x1 = fmaf(-2.0f, __builtin_amdgcn_rcpf(1.0f + __expf(accT[nt][1])), 1.0f);
                float x2 = fmaf(-2.0f, __builtin_amdgcn_rcpf(1.0f + __expf(accT[nt][2])), 1.0f);
                float x3 = fmaf(-2.0f, __builtin_amdgcn_rcpf(1.0f + __expf(accT[nt][3])), 1.0f);
                pk[nt][0] = cvt_pk_bf16(x0, x1);
                pk[nt][1] = cvt_pk_bf16(x2, x3);
            }
            floatx4 acc2 = {0.f, 0.f, 0.f, 0.f};
            #pragma unroll
            for (int kt = 0; kt < 4; ++kt) {
                int lo0 = __builtin_amdgcn_ds_bpermute(addrA, (int)pk[2 * kt][0]);
                int hi0 = __builtin_amdgcn_ds_bpermute(addrA, (int)pk[2 * kt + 1][0]);
                int lo1 = __builtin_amdgcn_ds_bpermute(addrA, (int)pk[2 * kt][1]);
                int hi1 = __builtin_amdgcn_ds_bpermute(addrA, (int)pk[2 * kt + 1][1]);
                int lo2 = __builtin_amdgcn_ds_bpermute(addrB, (int)pk[2 * kt][0]);
                int hi2 = __builtin_amdgcn_ds_bpermute(addrB, (int)pk[2 * kt + 1][0]);
                int lo3 = __builtin_amdgcn_ds_bpermute(addrB, (int)pk[2 * kt][1]);
                int hi3 = __builtin_amdgcn_ds_bpermute(addrB, (int)pk[2 * kt + 1][1]);
                union { unsigned int u[4]; short8 s; } a2u;
                a2u.u[0] = (unsigned int)(hiSel ? hi0 : lo0);
                a2u.u[1] = (unsigned int)(hiSel ? hi1 : lo1);
                a2u.u[2] = (unsigned int)(hiSel ? hi2 : lo2);
                a2u.u[3] = (unsigned int)(hiSel ? hi3 : lo3);
                acc2 = __builtin_amdgcn_mfma_f32_16x16x32_bf16(a2u.s, pkW2[kt * 64 + lane], acc2, 0, 0, 0);
            }
            #pragma unroll
            for (int rr = 0; rr < 4; ++rr) {
                int lrow = tile * 16 + q * 4 + rr;     // 0..191
                int et = lrow / 3, i = lrow - et * 3;
                long ge = blockbase + et;
                float base = states[ge * 48 + i * 16 + m];
                out[ge * OUTD + i * 16 + m] = acc2[rr] + base + b2v;
            }
        }
    }
}

extern "C" void kernel_launch(void* const* d_in, const int* in_sizes, int n_in,
                              void* d_out, int out_size, void* d_ws, size_t ws_size,
                              hipStream_t stream) {
    const float* states = (const float*)d_in[0];
    const float* action = (const float*)d_in[1];
    const int* block_id = (const int*)d_in[2];
    const float* Wq = (const float*)d_in[3];
    const float* bq = (const float*)d_in[4];
    const float* Wk = (const float*)d_in[5];
    const float* bk = (const float*)d_in[6];
    const float* Wv = (const float*)d_in[7];
    const float* bv = (const float*)d_in[8];
    const float* W1 = (const float*)d_in[9];
    const float* b1 = (const float*)d_in[10];
    const float* W2 = (const float*)d_in[11];
    const float* b2 = (const float*)d_in[12];
    const float* Wc1 = (const float*)d_in[13];
    const float* bc1 = (const float*)d_in[14];
    const float* Wc2 = (const float*)d_in[15];
    const float* bc2 = (const float*)d_in[16];
    float* out = (float*)d_out;
    float* ws = (float*)d_ws;

    hipLaunchKernelGGL(prep_dots, dim3((NDOT + 3) / 4), dim3(256), 0, stream,
                       Wq, bq, Wk, bk, Wv, bv, W1, b1, ws);
    hipLaunchKernelGGL(prep_copy, dim3((NCOPY + 255) / 256), dim3(256), 0, stream,
                       W2, b2, Wc1, bc1, Wc2, bc2, ws);
    hipLaunchKernelGGL(main_kernel, dim3(BTOT / 64), dim3(256), 0, stream,
                       states, action, block_id, ws, out);
}

// Round 9
// 165.468 us; speedup vs baseline: 1.3606x; 1.3606x over previous
//
#include <hip/hip_runtime.h>
#include <math.h>

#define BTOT 131072
#define NBK 3
#define SS 16
#define NA 9
#define BAD 25      // SS+NA
#define STR 28      // padded row stride in the fp32 weight image
#define VD 128
#define CM 10
#define OUTD 51     // NBK*SS + 3
#define EPS 1e-8f

// ---- fp32 folded-weight image (float offsets in ws) ----
#define O_GQK  0        // 25 x 28  full Wq^T Wk
#define O_GQQ  700      // 25 x 28  lower-tri (off-diag x2) of Wq^T Wq
#define O_GKK  1400     // 25 x 28  lower-tri (off-diag x2) of Wk^T Wk
#define O_V1   2100     // 28: Wq^T bk
#define O_V2   2128     // 28: Wk^T bq
#define O_VQ   2156     // 28: Wq^T bq
#define O_VK   2184     // 28: Wk^T bk
#define O_C    2212     // c0, cq, ck, pad
#define O_M    2216     // (dead region)
#define O_B2   7976     // 16
#define O_WC1  7992     // 10 x 84
#define O_BC1  8832     // 12
#define O_WC2  8844     // 3 x 12
#define O_BC2  8880     // 4
#define LDS_F  8884
// ---- bf16 MFMA-packed B-fragments appended after the fp32 image ----
#define O_PKM  LDS_F          // 4096 ushorts = 2048 floats
#define O_PKW2 (LDS_F + 2048) // 2048 ushorts = 1024 floats
#define PKM_N  4096
#define PKW2_N 2048

#define NDOT  (O_M + PKM_N)   // 2216 fp32 dots + 4096 pkM dots
#define NCOPY (16 + 840 + 12 + 36 + 4 + PKW2_N)

typedef __attribute__((ext_vector_type(8))) short short8;
typedef __attribute__((ext_vector_type(4))) float floatx4;

__device__ __forceinline__ float fast_sigmoid(float x) {
    return __builtin_amdgcn_rcpf(1.0f + __expf(-x));
}

__device__ __forceinline__ unsigned short f2bf(float f) {
    unsigned int u = __float_as_uint(f);
    u += 0x7FFFu + ((u >> 16) & 1u);   // round-to-nearest-even
    return (unsigned short)(u >> 16);
}

__device__ __forceinline__ unsigned int cvt_pk_bf16(float lo, float hi) {
    unsigned int r;
    asm("v_cvt_pk_bf16_f32 %0, %1, %2" : "=v"(r) : "v"(lo), "v"(hi));
    return r;
}

// Pair exchange (lane^1) as quad_perm DPP [1,0,3,2] = 0xB1: 1-cycle VALU.
// __shfl_xor lowers to ds_swizzle (LDS pipe, ~120cy latency) — r5 had ~20 of
// those on the softmax-critical path. DPP verified correct in r2/r8.
__device__ __forceinline__ float dpp_xor1(float x) {
    return __int_as_float(__builtin_amdgcn_mov_dpp(__float_as_int(x), 0xB1, 0xF, 0xF, false));
}

// ---------------- prep: wave-per-output 128-length dot products ----------------
__global__ __launch_bounds__(256) void prep_dots(
    const float* __restrict__ Wq, const float* __restrict__ bq,
    const float* __restrict__ Wk, const float* __restrict__ bk,
    const float* __restrict__ Wv, const float* __restrict__ bv,
    const float* __restrict__ W1, const float* __restrict__ b1,
    float* __restrict__ ws) {
    int lane = threadIdx.x & 63;
    int gidx = blockIdx.x * 4 + (threadIdx.x >> 6);
    if (gidx >= NDOT) return;

    const float* pa = bq;  const float* pb = bk;   // safe defaults
    int sa = 1, sb = 1;
    float scale = 1.0f, bias = 0.0f;
    bool zero = false;
    bool isbf = false; int bfpos = 0;

    if (gidx < O_M) {
        int idx = gidx;
        if (idx < O_GQQ) {
            int e = idx / STR, f = idx % STR;
            if (f < BAD) { pa = Wq + e; sa = BAD; pb = Wk + f; sb = BAD; }
            else zero = true;
        } else if (idx < O_GKK) {
            int j = idx - O_GQQ; int e = j / STR, f = j % STR;
            if (f < BAD && f <= e) { pa = Wq + e; sa = BAD; pb = Wq + f; sb = BAD; scale = (f == e) ? 1.0f : 2.0f; }
            else zero = true;
        } else if (idx < O_V1) {
            int j = idx - O_GKK; int e = j / STR, f = j % STR;
            if (f < BAD && f <= e) { pa = Wk + e; sa = BAD; pb = Wk + f; sb = BAD; scale = (f == e) ? 1.0f : 2.0f; }
            else zero = true;
        } else if (idx < O_V2) {
            int e = idx - O_V1;
            if (e < BAD) { pa = Wq + e; sa = BAD; pb = bk; }
            else zero = true;
        } else if (idx < O_VQ) {
            int e = idx - O_V2;
            if (e < BAD) { pa = Wk + e; sa = BAD; pb = bq; }
            else zero = true;
        } else if (idx < O_VK) {
            int e = idx - O_VQ;
            if (e < BAD) { pa = Wq + e; sa = BAD; pb = bq; }
            else zero = true;
        } else if (idx < O_C) {
            int e = idx - O_VK;
            if (e < BAD) { pa = Wk + e; sa = BAD; pb = bk; }
            else zero = true;
        } else {
            int j = idx - O_C;
            if (j == 0)      { pa = bq; pb = bk; }
            else if (j == 1) { pa = bq; pb = bq; }
            else if (j == 2) { pa = bk; pb = bk; }
            else zero = true;
        }
    } else {
        // pkM B-frag: B[k][n], n = tile*16 + (l&15), k = (l>>4)*8 + j
        int p = gidx - O_M;
        isbf = true; bfpos = p;
        int l2 = (p >> 3) & 63, j = p & 7;
        int n = (p >> 9) * 16 + (l2 & 15);
        int k = ((l2 >> 4) << 3) + j;
        if (k < BAD)       { pa = W1 + n * VD; pb = Wv + k; sb = BAD; scale = 2.0f; }
        else if (k == BAD) { pa = W1 + n * VD; pb = bv; scale = 2.0f; bias = 2.0f * b1[n]; }
        else zero = true;
    }

    float s = 0.0f;
    if (!zero)
        s = pa[sa * lane] * pb[sb * lane] + pa[sa * (lane + 64)] * pb[sb * (lane + 64)];
    #pragma unroll
    for (int off = 1; off < 64; off <<= 1) s += __shfl_xor(s, off);
    float val = zero ? 0.0f : (s * scale + bias);
    if (lane == 0) {
        if (isbf) ((unsigned short*)(ws + O_PKM))[bfpos] = f2bf(val);
        else ws[gidx] = val;
    }
}

__global__ __launch_bounds__(256) void prep_copy(
    const float* __restrict__ W2, const float* __restrict__ b2,
    const float* __restrict__ Wc1, const float* __restrict__ bc1,
    const float* __restrict__ Wc2, const float* __restrict__ bc2,
    float* __restrict__ ws) {
    int c = blockIdx.x * 256 + threadIdx.x;
    if (c >= NCOPY) return;
    if (c < 16) { ws[O_B2 + c] = b2[c]; return; }
    c -= 16;
    if (c < 840) {
        int m = c / 84, r = c % 84, i = r / STR, f = r % STR;
        ws[O_WC1 + c] = (f < BAD) ? Wc1[m * (NBK * BAD) + i * BAD + f] : 0.0f;
        return;
    }
    c -= 840;
    if (c < 12) { ws[O_BC1 + c] = (c < CM) ? bc1[c] : 0.0f; return; }
    c -= 12;
    if (c < 36) { int o = c / 12, mm = c % 12; ws[O_WC2 + c] = (mm < CM) ? Wc2[o * CM + mm] : 0.0f; return; }
    c -= 36;
    if (c < 4) { ws[O_BC2 + c] = (c < 3) ? bc2[c] : 0.0f; return; }
    c -= 4;
    // pkW2 B-frag: B[k][o], o = l&15, k = kt*32 + (l>>4)*8 + j
    int kt = c >> 9, l = (c >> 3) & 63, j = c & 7;
    int o = l & 15;
    int k = kt * 32 + ((l >> 4) << 3) + j;
    ((unsigned short*)(ws + O_PKW2))[c] = f2bf(W2[o * VD + k]);
}

// ---------------- fused main kernel: r5 base + DPP exchange + cvt_pk pack ----
// Exact round-5 structure (70.2 us verified best): 2 lanes per element
// (h = t&1), split phase-1 work, verified MFMA phase 2 (6 tiles/wave).
// Changes vs r5 (both from verified toolbox, numerics-identical):
//  1. all pair exchanges use quad_perm DPP (dpp_xor1) instead of __shfl_xor
//     -> removes ~20 ds_swizzle LDS round-trips from the softmax-critical path
//  2. a_tilde bf16 pack via v_cvt_pk_bf16_f32 (bit-identical RNE to f2bf)
__global__ __launch_bounds__(256) void main_kernel(
    const float* __restrict__ states, const float* __restrict__ action,
    const int* __restrict__ block_id,
    const float* __restrict__ ws, float* __restrict__ out) {
    __shared__ __align__(16) unsigned short At[384 * 40];   // 30720 B

    int t = threadIdx.x;
    int lane = t & 63;
    int h = t & 1;
    int le = t >> 1;                        // local element 0..127
    long elem = (long)blockIdx.x * 128 + le;

    const float* st = states + elem * (NBK * SS);
    const float* ac = action + elem * NA;
    const int* bid = block_id + elem * NBK;

    // ---- build ba[3][25] (both lanes of the pair; compile-time indices) ----
    float ba[NBK * BAD];
    #pragma unroll
    for (int i = 0; i < NBK; ++i) {
        const float4* s4 = (const float4*)(st + i * SS);
        #pragma unroll
        for (int w4 = 0; w4 < 4; ++w4) {
            float4 v = s4[w4];
            ba[i * BAD + w4 * 4 + 0] = v.x;
            ba[i * BAD + w4 * 4 + 1] = v.y;
            ba[i * BAD + w4 * 4 + 2] = v.z;
            ba[i * BAD + w4 * 4 + 3] = v.w;
        }
        bool sel = (bid[i] == 1);
        #pragma unroll
        for (int c = 0; c < NA; ++c)
            ba[i * BAD + SS + c] = sel ? ac[c] : -1.0f;
    }

    // ---- confidence MLP: h computes its 5 hidden units, DPP exchange ----
    {
        const float* wc = ws + O_WC1 + h * 5 * 84;   // per-lane base
        const float* bc = ws + O_BC1 + h * 5;
        float hp[5];
        #pragma unroll
        for (int k = 0; k < 5; ++k) {
            float s = bc[k];
            #pragma unroll
            for (int i = 0; i < NBK; ++i)
                #pragma unroll
                for (int f = 0; f < BAD; ++f)
                    s += wc[k * 84 + i * STR + f] * ba[i * BAD + f];
            hp[k] = fast_sigmoid(s);
        }
        float op5[5];
        #pragma unroll
        for (int k = 0; k < 5; ++k) op5[k] = dpp_xor1(hp[k]);
        if (h == 0) {
            float* op = out + elem * OUTD;
            #pragma unroll
            for (int o = 0; o < 3; ++o) {
                float s = ws[O_BC2 + o];
                #pragma unroll
                for (int m = 0; m < 5; ++m) s += ws[O_WC2 + o * 12 + m] * hp[m];
                #pragma unroll
                for (int m = 0; m < 5; ++m) s += ws[O_WC2 + o * 12 + 5 + m] * op5[m];
                op[48 + o] = fast_sigmoid(s);
            }
        }
    }

    // ---- linear terms: h=0 -> s1(V1), dq(VQ); h=1 -> s2(V2), dk(VK) ----
    float sl[NBK], dd[NBK];
    {
        const float* vA = ws + (h ? O_V2 : O_V1);
        const float* vB = ws + (h ? O_VK : O_VQ);
        #pragma unroll
        for (int p = 0; p < NBK; ++p) {
            float sA = 0.f, sB = 0.f;
            #pragma unroll
            for (int e = 0; e < BAD; ++e) {
                float b = ba[p * BAD + e];
                sA = fmaf(vA[e], b, sA);
                sB = fmaf(vB[e], b, sB);
            }
            sl[p] = sA; dd[p] = sB;
        }
    }

    // ---- bilinear numerators: interleaved e split (h=0 even, h=1 odd) ----
    float nm[NBK][NBK] = {{0.f,0.f,0.f},{0.f,0.f,0.f},{0.f,0.f,0.f}};
    {
        const float* gq = ws + O_GQK + h * STR;   // per-lane base (row h)
        #pragma unroll
        for (int i13 = 0; i13 < 13; ++i13) {
            // e = 2*i13 + h; for i13==12: ec=24 for both lanes, h=1 zeroed
            const float* grow = (i13 == 12) ? (ws + O_GQK + 24 * STR)
                                            : (gq + i13 * 2 * STR);
            float t0 = 0.f, t1 = 0.f, t2 = 0.f;
            #pragma unroll
            for (int f = 0; f < BAD; ++f) {
                float g = grow[f];
                t0 = fmaf(g, ba[0 * BAD + f], t0);
                t1 = fmaf(g, ba[1 * BAD + f], t1);
                t2 = fmaf(g, ba[2 * BAD + f], t2);
            }
            float zs = (i13 == 12) ? (1.0f - (float)h) : 1.0f;
            #pragma unroll
            for (int i = 0; i < NBK; ++i) {
                float be;
                if (i13 == 12) be = ba[i * BAD + 24] * zs;
                else {
                    float b_even = ba[i * BAD + 2 * i13];
                    float b_odd  = ba[i * BAD + 2 * i13 + 1];
                    be = h ? b_odd : b_even;
                }
                nm[i][0] = fmaf(be, t0, nm[i][0]);
                nm[i][1] = fmaf(be, t1, nm[i][1]);
                nm[i][2] = fmaf(be, t2, nm[i][2]);
            }
        }
        // combine halves (DPP, VALU-rate)
        #pragma unroll
        for (int i = 0; i < NBK; ++i)
            #pragma unroll
            for (int j = 0; j < NBK; ++j)
                nm[i][j] += dpp_xor1(nm[i][j]);
    }

    // ---- quadratic triangle: h=0 GQQ (qn2), h=1 GKK (kn2) ----
    float rn[NBK];
    {
        const float* gt = ws + (h ? O_GKK : O_GQQ);   // per-lane base
        float sn2[NBK] = {0.f, 0.f, 0.f};
        #pragma unroll
        for (int e = 0; e < BAD; ++e) {
            float p0 = 0.f, p1 = 0.f, p2 = 0.f;
            #pragma unroll
            for (int f = 0; f <= e; ++f) {
                float g = gt[e * STR + f];
                p0 = fmaf(g, ba[0 * BAD + f], p0);
                p1 = fmaf(g, ba[1 * BAD + f], p1);
                p2 = fmaf(g, ba[2 * BAD + f], p2);
            }
            sn2[0] = fmaf(ba[0 * BAD + e], p0, sn2[0]);
            sn2[1] = fmaf(ba[1 * BAD + e], p1, sn2[1]);
            sn2[2] = fmaf(ba[2 * BAD + e], p2, sn2[2]);
        }
        float cc = ws[O_C + 1 + h];                   // cq or ck
        #pragma unroll
        for (int p = 0; p < NBK; ++p) {
            sn2[p] += 2.0f * dd[p] + cc;
            rn[p] = __builtin_amdgcn_sqrtf(fmaxf(sn2[p], 0.0f));
        }
    }

    // ---- exchange row norms and linear sums across the pair (DPP) ----
    float orn[NBK], osl[NBK];
    #pragma unroll
    for (int p = 0; p < NBK; ++p) {
        orn[p] = dpp_xor1(rn[p]);
        osl[p] = dpp_xor1(sl[p]);
    }
    float s1v[NBK], s2v[NBK], qv[NBK], kv[NBK];
    #pragma unroll
    for (int p = 0; p < NBK; ++p) {
        s1v[p] = h ? osl[p] : sl[p];
        s2v[p] = h ? sl[p] : osl[p];
        qv[p]  = h ? orn[p] : rn[p];
        kv[p]  = h ? rn[p] : orn[p];
    }
    float c0 = ws[O_C + 0];

    // ---- softmax over j (duplicated on both lanes; cheap) ----
    float att[NBK][NBK];
    #pragma unroll
    for (int i = 0; i < NBK; ++i) {
        float dv[NBK];
        #pragma unroll
        for (int j = 0; j < NBK; ++j)
            dv[j] = (nm[i][j] + s1v[i] + s2v[j] + c0) *
                    __builtin_amdgcn_rcpf(fmaxf(qv[i] * kv[j], EPS));
        float mx = fmaxf(dv[0], fmaxf(dv[1], dv[2]));
        float e0 = __expf(dv[0] - mx);
        float e1 = __expf(dv[1] - mx);
        float e2 = __expf(dv[2] - mx);
        float inv = __builtin_amdgcn_rcpf(e0 + e1 + e2);
        att[i][0] = e0 * inv;
        att[i][1] = e1 * inv;
        att[i][2] = e2 * inv;
    }

    // ---- a_tilde + cvt_pk_bf16 pack + LDS write: e-range split ----
    // h=0: e 0..11 -> dwords 0..5 (+ zero dwords 13..15)
    // h=1: e 12..23 -> dwords 6..11; e24+bias -> dword 12
    #pragma unroll
    for (int i = 0; i < NBK; ++i) {
        unsigned int* dst = (unsigned int*)&At[(le * 3 + i) * 40];
        #pragma unroll
        for (int d = 0; d < 6; ++d) {
            float a_lo = ba[0 * BAD + 2 * d]     * att[i][0] + ba[1 * BAD + 2 * d]     * att[i][1] + ba[2 * BAD + 2 * d]     * att[i][2];
            float a_hi = ba[0 * BAD + 2 * d + 1] * att[i][0] + ba[1 * BAD + 2 * d + 1] * att[i][1] + ba[2 * BAD + 2 * d + 1] * att[i][2];
            float b_lo = ba[0 * BAD + 12 + 2 * d]     * att[i][0] + ba[1 * BAD + 12 + 2 * d]     * att[i][1] + ba[2 * BAD + 12 + 2 * d]     * att[i][2];
            float b_hi = ba[0 * BAD + 12 + 2 * d + 1] * att[i][0] + ba[1 * BAD + 12 + 2 * d + 1] * att[i][1] + ba[2 * BAD + 12 + 2 * d + 1] * att[i][2];
            float v_lo = h ? b_lo : a_lo;
            float v_hi = h ? b_hi : a_hi;
            dst[h * 6 + d] = cvt_pk_bf16(v_lo, v_hi);
        }
        if (h) {
            float v24 = ba[0 * BAD + 24] * att[i][0] + ba[1 * BAD + 24] * att[i][1] + ba[2 * BAD + 24] * att[i][2];
            dst[12] = cvt_pk_bf16(v24, 1.0f);   // hi = bf16(1.0) = 0x3F80
        } else {
            dst[13] = 0u; dst[14] = 0u; dst[15] = 0u;
        }
    }

    // At is wave-private: pair lanes and phase-2 tiles belong to the same wave.
    asm volatile("s_waitcnt lgkmcnt(0)" ::: "memory");

    // ================= phase 2: MFMA (6 tiles per wave, verified path) =======
    {
        int w = t >> 6;
        int m = lane & 15, q = lane >> 4;
        const short8* pkM = (const short8*)(ws + O_PKM);
        const short8* pkW2 = (const short8*)(ws + O_PKW2);
        float b2v = ws[O_B2 + m];
        long blockbase = (long)blockIdx.x * 128;
        int addrA = ((q & 1) ? (m + 32) : m) << 2;
        int addrB = addrA + 64;
        bool hiSel = (q >= 2);

        for (int tt = 0; tt < 6; ++tt) {
            int tile = w * 6 + tt;            // rows tile*16 .. +15 (0..383)
            short8 af = *(const short8*)&At[(tile * 16 + m) * 40 + q * 8];
            floatx4 accT[8];
            #pragma unroll
            for (int nt = 0; nt < 8; ++nt) {
                floatx4 z = {0.f, 0.f, 0.f, 0.f};
                accT[nt] = __builtin_amdgcn_mfma_f32_16x16x32_bf16(pkM[nt * 64 + lane], af, z, 0, 0, 0);
            }
            unsigned int pk[8][2];
            #pragma unroll
            for (int nt = 0; nt < 8; ++nt) {
                float x0 = fmaf(-2.0f, __builtin_amdgcn_rcpf(1.0f + __expf(accT[nt][0])), 1.0f);
                float x1 = fmaf(-2.0f, __builtin_amdgcn_rcpf(1.0f + __expf(accT[nt][1])), 1.0f);
                float x2 = fmaf(-2.0f, __builtin_amdgcn_rcpf(1.0f + __expf(accT[nt][2])), 1.0f);
                float x3 = fmaf(-2.0f, __builtin_amdgcn_rcpf(1.0f + __expf(accT[nt][3])), 1.0f);
                pk[nt][0] = cvt_pk_bf16(x0, x1);
                pk[nt][1] = cvt_pk_bf16(x2, x3);
            }
            floatx4 acc2 = {0.f, 0.f, 0.f, 0.f};
            #pragma unroll
            for (int kt = 0; kt < 4; ++kt) {
                int lo0 = __builtin_amdgcn_ds_bpermute(addrA, (int)pk[2 * kt][0]);
                int hi0 = __builtin_amdgcn_ds_bpermute(addrA, (int)pk[2 * kt + 1][0]);
                int lo1 = __builtin_amdgcn_ds_bpermute(addrA, (int)pk[2 * kt][1]);
                int hi1 = __builtin_amdgcn_ds_bpermute(addrA, (int)pk[2 * kt + 1][1]);
                int lo2 = __builtin_amdgcn_ds_bpermute(addrB, (int)pk[2 * kt][0]);
                int hi2 = __builtin_amdgcn_ds_bpermute(addrB, (int)pk[2 * kt + 1][0]);
                int lo3 = __builtin_amdgcn_ds_bpermute(addrB, (int)pk[2 * kt][1]);
                int hi3 = __builtin_amdgcn_ds_bpermute(addrB, (int)pk[2 * kt + 1][1]);
                union { unsigned int u[4]; short8 s; } a2u;
                a2u.u[0] = (unsigned int)(hiSel ? hi0 : lo0);
                a2u.u[1] = (unsigned int)(hiSel ? hi1 : lo1);
                a2u.u[2] = (unsigned int)(hiSel ? hi2 : lo2);
                a2u.u[3] = (unsigned int)(hiSel ? hi3 : lo3);
                acc2 = __builtin_amdgcn_mfma_f32_16x16x32_bf16(a2u.s, pkW2[kt * 64 + lane], acc2, 0, 0, 0);
            }
            #pragma unroll
            for (int rr = 0; rr < 4; ++rr) {
                int lrow = tile * 16 + q * 4 + rr;     // 0..383
                int et = lrow / 3, i = lrow - et * 3;
                long ge = blockbase + et;
                float base = states[ge * 48 + i * 16 + m];
                out[ge * OUTD + i * 16 + m] = acc2[rr] + base + b2v;
            }
        }
    }
}

extern "C" void kernel_launch(void* const* d_in, const int* in_sizes, int n_in,
                              void* d_out, int out_size, void* d_ws, size_t ws_size,
                              hipStream_t stream) {
    const float* states = (const float*)d_in[0];
    const float* action = (const float*)d_in[1];
    const int* block_id = (const int*)d_in[2];
    const float* Wq = (const float*)d_in[3];
    const float* bq = (const float*)d_in[4];
    const float* Wk = (const float*)d_in[5];
    const float* bk = (const float*)d_in[6];
    const float* Wv = (const float*)d_in[7];
    const float* bv = (const float*)d_in[8];
    const float* W1 = (const float*)d_in[9];
    const float* b1 = (const float*)d_in[10];
    const float* W2 = (const float*)d_in[11];
    const float* b2 = (const float*)d_in[12];
    const float* Wc1 = (const float*)d_in[13];
    const float* bc1 = (const float*)d_in[14];
    const float* Wc2 = (const float*)d_in[15];
    const float* bc2 = (const float*)d_in[16];
    float* out = (float*)d_out;
    float* ws = (float*)d_ws;

    hipLaunchKernelGGL(prep_dots, dim3((NDOT + 3) / 4), dim3(256), 0, stream,
                       Wq, bq, Wk, bk, Wv, bv, W1, b1, ws);
    hipLaunchKernelGGL(prep_copy, dim3((NCOPY + 255) / 256), dim3(256), 0, stream,
                       W2, b2, Wc1, bc1, Wc2, bc2, ws);
    hipLaunchKernelGGL(main_kernel, dim3(BTOT / 128), dim3(256), 0, stream,
                       states, action, block_id, ws, out);
}